// Round 5
// baseline (761.906 us; speedup 1.0000x reference)
//
#include <hip/hip_runtime.h>
#include <hip/hip_bf16.h>

typedef __hip_bfloat16 bf16;
typedef unsigned int uint;

#define NATOMS 20000
#define NEDGES 640000
#define FD 128
#define F3 384
#define NR 20
#define APB 8

// f32 -> bf16 bits with round-to-nearest-even
__device__ __forceinline__ uint f2bfu(float f) {
  const uint u = __float_as_uint(f);
  return (u + 0x7FFFu + ((u >> 16) & 1u)) >> 16;
}
__device__ __forceinline__ float bflo(uint u) { return __uint_as_float(u << 16); }
__device__ __forceinline__ float bfhi(uint u) { return __uint_as_float(u & 0xFFFF0000u); }

// ---------------------------------------------------------------------------
// CSR build: histogram -> exclusive scan; scatter fused with edge-prep.
// ---------------------------------------------------------------------------
__global__ __launch_bounds__(256) void hist_kernel(const int* __restrict__ eidx,
                                                   int* __restrict__ cnt) {
  const int e = blockIdx.x * 256 + threadIdx.x;
  if (e < NEDGES) atomicAdd(&cnt[eidx[e]], 1);
}

__global__ __launch_bounds__(512) void scan_kernel(const int* __restrict__ cnt,
                                                   int* __restrict__ off) {
  __shared__ int part[512];
  const int t = threadIdx.x;
  const int CH = (NATOMS + 511) / 512;   // 40
  const int base = t * CH;
  int s = 0;
  for (int k = 0; k < CH; ++k) {
    const int idx = base + k;
    if (idx < NATOMS) s += cnt[idx];
  }
  part[t] = s;
  __syncthreads();
  if (t == 0) {
    int run = 0;
    for (int i = 0; i < 512; ++i) { const int tmp = part[i]; part[i] = run; run += tmp; }
    off[NATOMS] = run;
  }
  __syncthreads();
  int run = part[t];
  for (int k = 0; k < CH; ++k) {
    const int idx = base + k;
    if (idx < NATOMS) { off[idx] = run; run += cnt[idx]; }
  }
}

// Scatter edge ids by destination + precompute per-edge basis packet:
// basisE[e] = 24 bf16: [0..19] sin((r+1)th)/d*env, [20] env, [21..23] dir.
// One sincos + one Chebyshev recurrence per EDGE (was: per edge per thread).
__global__ __launch_bounds__(256) void scatter_prep_kernel(
    const int* __restrict__ eidx, const float* __restrict__ ew,
    int* __restrict__ cursor, int* __restrict__ sorted, uint* __restrict__ basisE)
{
  const int e = blockIdx.x * 256 + threadIdx.x;
  if (e >= NEDGES) return;
  const int pos = atomicAdd(&cursor[eidx[e]], 1);
  sorted[pos] = e;

  const float w0 = ew[(size_t)e * 3 + 0];
  const float w1 = ew[(size_t)e * 3 + 1];
  const float w2 = ew[(size_t)e * 3 + 2];
  const float d = sqrtf(w0 * w0 + w1 * w1 + w2 * w2);
  const float invd = 1.f / d;
  float s1, c1;
  __sincosf(d * 0.628318530717958f, &s1, &c1);   // theta = pi*d/5
  const float env = (d < 5.0f) ? 0.5f * (c1 + 1.f) : 0.f;
  const float scale = env * invd;

  float vals[24];
  float sprev = 0.f, scur = s1;
  const float twoc = 2.f * c1;
  #pragma unroll
  for (int r = 0; r < NR; ++r) {
    vals[r] = scur * scale;
    const float sn = twoc * scur - sprev;
    sprev = scur; scur = sn;
  }
  vals[20] = env;
  vals[21] = w0 * invd; vals[22] = w1 * invd; vals[23] = w2 * invd;

  uint u[12];
  #pragma unroll
  for (int k = 0; k < 12; ++k)
    u[k] = f2bfu(vals[2 * k]) | (f2bfu(vals[2 * k + 1]) << 16);
  uint4* bp = (uint4*)(basisE + (size_t)e * 12);
  bp[0] = make_uint4(u[0], u[1], u[2], u[3]);
  bp[1] = make_uint4(u[4], u[5], u[6], u[7]);
  bp[2] = make_uint4(u[8], u[9], u[10], u[11]);
}

// ---------------------------------------------------------------------------
// Phase 1: x = silu(q @ W1 + b1) @ W2 + b2  -> bf16 x[N,384]
// ---------------------------------------------------------------------------
__global__ __launch_bounds__(128) void mlp_kernel(
    const float* __restrict__ q, const float* __restrict__ W1, const float* __restrict__ b1,
    const float* __restrict__ W2, const float* __restrict__ b2v, bf16* __restrict__ x)
{
  __shared__ float qL[APB][FD];
  __shared__ float hL[APB][FD];
  const int t = threadIdx.x;
  const int a0 = blockIdx.x * APB;

  #pragma unroll
  for (int a = 0; a < APB; ++a) qL[a][t] = q[(size_t)(a0 + a) * FD + t];
  __syncthreads();

  float hacc[APB];
  const float bb1 = b1[t];
  #pragma unroll
  for (int a = 0; a < APB; ++a) hacc[a] = bb1;

  for (int i = 0; i < FD; ++i) {
    const float w = W1[(size_t)i * FD + t];
    #pragma unroll
    for (int a = 0; a < APB; ++a) hacc[a] += qL[a][i] * w;
  }
  #pragma unroll
  for (int a = 0; a < APB; ++a) hL[a][t] = hacc[a] / (1.f + __expf(-hacc[a]));
  __syncthreads();

  float x0[APB], x1[APB], x2[APB];
  const float c0 = b2v[t], c1 = b2v[FD + t], c2 = b2v[2 * FD + t];
  #pragma unroll
  for (int a = 0; a < APB; ++a) { x0[a] = c0; x1[a] = c1; x2[a] = c2; }

  for (int i = 0; i < FD; ++i) {
    const float w0 = W2[(size_t)i * F3 + t];
    const float w1 = W2[(size_t)i * F3 + FD + t];
    const float w2 = W2[(size_t)i * F3 + 2 * FD + t];
    #pragma unroll
    for (int a = 0; a < APB; ++a) {
      const float hv = hL[a][i];
      x0[a] += hv * w0; x1[a] += hv * w1; x2[a] += hv * w2;
    }
  }
  #pragma unroll
  for (int a = 0; a < APB; ++a) {
    const int n = a0 + a;
    x[(size_t)n * F3 + t]          = __float2bfloat16(x0[a]);
    x[(size_t)n * F3 + FD + t]     = __float2bfloat16(x1[a]);
    x[(size_t)n * F3 + 2 * FD + t] = __float2bfloat16(x2[a]);
  }
}

// ---------------------------------------------------------------------------
// Phase 2: one block (384 threads = 6 waves) per destination atom.
// Thread t owns output column t: only 21 Wf registers -> no spill.
// channel = t>>7 (wave-uniform): 0 -> q, 1 -> dmuR*dir, 2 -> dmumu*mu.
// Basis packet read via uniform s_load; bf16 unpack on scalar pipe.
// ---------------------------------------------------------------------------
__global__ __launch_bounds__(384) void gather_kernel(
    const float* __restrict__ q, const float* __restrict__ mu, const bf16* __restrict__ x,
    const int* __restrict__ eidx, const uint* __restrict__ basisE,
    const float* __restrict__ Wf, const float* __restrict__ bfv,
    const int* __restrict__ off, const int* __restrict__ sorted,
    float* __restrict__ out)
{
  const int t = threadIdx.x;
  const int i = blockIdx.x;
  const int ch = t >> 7;       // 0,1,2 — wave-uniform
  const int c  = t & (FD - 1);

  float wf[NR];
  #pragma unroll
  for (int r = 0; r < NR; ++r) wf[r] = Wf[(size_t)r * F3 + t];
  const float bias = bfv[t];

  float acc0 = 0.f, acc1 = 0.f, acc2 = 0.f;
  const int beg = off[i], end = off[i + 1];

  for (int p = beg; p < end; ++p) {
    const int e = __builtin_amdgcn_readfirstlane(sorted[p]);
    const int j = __builtin_amdgcn_readfirstlane(eidx[NEDGES + e]);
    const uint* bp = basisE + (size_t)e * 12;
    uint u[12];
    #pragma unroll
    for (int k = 0; k < 12; ++k) u[k] = bp[k];   // uniform -> s_load_dwordx4 x3

    const float env = bflo(u[10]);
    float f = env * bias;
    #pragma unroll
    for (int r = 0; r < 10; ++r) {
      f += bflo(u[r]) * wf[2 * r];
      f += bfhi(u[r]) * wf[2 * r + 1];
    }

    const float xv = __bfloat162float(x[(size_t)j * F3 + t]);
    if (ch == 0) {
      acc0 += f * xv;                          // dq
    } else if (ch == 1) {
      const float dmuR = f * xv;
      acc0 += dmuR * bfhi(u[10]);              // dir0
      acc1 += dmuR * bflo(u[11]);              // dir1
      acc2 += dmuR * bfhi(u[11]);              // dir2
    } else {
      const float dmumu = f * xv;
      const float* mj = mu + (size_t)j * F3;
      acc0 += dmumu * mj[c];
      acc1 += dmumu * mj[FD + c];
      acc2 += dmumu * mj[2 * FD + c];
    }
  }

  __shared__ float tmp[3][FD];
  if (ch == 1) { tmp[0][c] = acc0; tmp[1][c] = acc1; tmp[2][c] = acc2; }
  __syncthreads();
  if (ch == 0) {
    out[(size_t)i * FD + c] = q[(size_t)i * FD + c] + acc0;
  } else if (ch == 2) {
    const size_t NQ = (size_t)NATOMS * FD;
    const size_t mi = (size_t)i * F3;
    out[NQ + mi + c]          = mu[mi + c]          + tmp[0][c] + acc0;
    out[NQ + mi + FD + c]     = mu[mi + FD + c]     + tmp[1][c] + acc1;
    out[NQ + mi + 2 * FD + c] = mu[mi + 2 * FD + c] + tmp[2][c] + acc2;
  }
}

extern "C" void kernel_launch(void* const* d_in, const int* in_sizes, int n_in,
                              void* d_out, int out_size, void* d_ws, size_t ws_size,
                              hipStream_t stream) {
  const float* q   = (const float*)d_in[0];
  const float* mu  = (const float*)d_in[1];
  const int*   eix = (const int*)d_in[2];
  const float* ew  = (const float*)d_in[3];
  const float* W1  = (const float*)d_in[4];
  const float* b1  = (const float*)d_in[5];
  const float* W2  = (const float*)d_in[6];
  const float* b2v = (const float*)d_in[7];
  const float* Wf  = (const float*)d_in[8];
  const float* bfv = (const float*)d_in[9];
  float* out = (float*)d_out;

  // Workspace (~48.9 MB): [basisE u32 E*12 | x bf16 N*384 | sorted E | off N+1 | cnt N | cursor N]
  char* w = (char*)d_ws;
  uint* basisE = (uint*)w;   w += (size_t)NEDGES * 12 * sizeof(uint);
  bf16* x      = (bf16*)w;   w += (size_t)NATOMS * F3 * sizeof(bf16);
  int*  sorted = (int*)w;    w += (size_t)NEDGES * sizeof(int);
  int*  off    = (int*)w;    w += (size_t)(NATOMS + 1) * sizeof(int);
  int*  cnt    = (int*)w;    w += (size_t)NATOMS * sizeof(int);
  int*  cursor = (int*)w;

  hipMemsetAsync(cnt, 0, (size_t)NATOMS * sizeof(int), stream);

  hist_kernel<<<(NEDGES + 255) / 256, 256, 0, stream>>>(eix, cnt);
  scan_kernel<<<1, 512, 0, stream>>>(cnt, off);
  hipMemcpyAsync(cursor, off, (size_t)NATOMS * sizeof(int),
                 hipMemcpyDeviceToDevice, stream);
  scatter_prep_kernel<<<(NEDGES + 255) / 256, 256, 0, stream>>>(eix, ew, cursor,
                                                                sorted, basisE);

  mlp_kernel<<<NATOMS / APB, 128, 0, stream>>>(q, W1, b1, W2, b2v, x);

  gather_kernel<<<NATOMS, 384, 0, stream>>>(q, mu, x, eix, basisE, Wf, bfv,
                                            off, sorted, out);
}

// Round 6
// 652.244 us; speedup vs baseline: 1.1681x; 1.1681x over previous
//
#include <hip/hip_runtime.h>
#include <hip/hip_bf16.h>

typedef __hip_bfloat16 bf16;
typedef unsigned int uint;

#define NATOMS 20000
#define NEDGES 640000
#define FD 128
#define F3 384
#define NR 20
#define APB 8

// f32 -> bf16 bits, round-to-nearest-even
__device__ __forceinline__ uint f2bfu(float f) {
  const uint u = __float_as_uint(f);
  return (u + 0x7FFFu + ((u >> 16) & 1u)) >> 16;
}
__device__ __forceinline__ float bflo(uint u) { return __uint_as_float(u << 16); }
__device__ __forceinline__ float bfhi(uint u) { return __uint_as_float(u & 0xFFFF0000u); }

#if defined(__has_builtin)
#if __has_builtin(__builtin_amdgcn_fdot2_f32_bf16)
#define HAVE_DOT2 1
#endif
#endif

#ifdef HAVE_DOT2
typedef __bf16 v2bf __attribute__((ext_vector_type(2)));
__device__ __forceinline__ float dot2acc(uint a, uint b, float acc) {
  return __builtin_amdgcn_fdot2_f32_bf16(__builtin_bit_cast(v2bf, a),
                                         __builtin_bit_cast(v2bf, b), acc, false);
}
#else
__device__ __forceinline__ float dot2acc(uint a, uint b, float acc) {
  return acc + bflo(a) * bflo(b) + bfhi(a) * bfhi(b);
}
#endif

// ---------------------------------------------------------------------------
// CSR build: histogram -> exclusive scan.
// ---------------------------------------------------------------------------
__global__ __launch_bounds__(256) void hist_kernel(const int* __restrict__ eidx,
                                                   int* __restrict__ cnt) {
  const int e = blockIdx.x * 256 + threadIdx.x;
  if (e < NEDGES) atomicAdd(&cnt[eidx[e]], 1);
}

__global__ __launch_bounds__(512) void scan_kernel(const int* __restrict__ cnt,
                                                   int* __restrict__ off) {
  __shared__ int part[512];
  const int t = threadIdx.x;
  const int CH = (NATOMS + 511) / 512;
  const int base = t * CH;
  int s = 0;
  for (int k = 0; k < CH; ++k) {
    const int idx = base + k;
    if (idx < NATOMS) s += cnt[idx];
  }
  part[t] = s;
  __syncthreads();
  if (t == 0) {
    int run = 0;
    for (int i = 0; i < 512; ++i) { const int tmp = part[i]; part[i] = run; run += tmp; }
    off[NATOMS] = run;
  }
  __syncthreads();
  int run = part[t];
  for (int k = 0; k < CH; ++k) {
    const int idx = base + k;
    if (idx < NATOMS) { off[idx] = run; run += cnt[idx]; }
  }
}

// ---------------------------------------------------------------------------
// Prep: per edge, compute basis packet and write the full 64B record DIRECTLY
// at its destination-sorted position. Record (16 dwords):
//  [0..9]  bf16 pairs: sin((r+1)th)/d*env  (r=0..19)
//  [10]    env (f32)   [11] j (int)   [12..14] dir (f32)   [15] pad
// ---------------------------------------------------------------------------
__global__ __launch_bounds__(256) void prep_kernel(
    const int* __restrict__ eidx, const float* __restrict__ ew,
    int* __restrict__ cursor, uint4* __restrict__ basisS)
{
  const int e = blockIdx.x * 256 + threadIdx.x;
  if (e >= NEDGES) return;
  const int i = eidx[e];
  const int j = eidx[NEDGES + e];
  const int pos = atomicAdd(&cursor[i], 1);

  const float w0 = ew[(size_t)e * 3 + 0];
  const float w1 = ew[(size_t)e * 3 + 1];
  const float w2 = ew[(size_t)e * 3 + 2];
  const float d = sqrtf(w0 * w0 + w1 * w1 + w2 * w2);
  const float invd = 1.f / d;
  float s1, c1;
  __sincosf(d * 0.628318530717958f, &s1, &c1);   // theta = pi*d/5
  const float env = (d < 5.f) ? 0.5f * (c1 + 1.f) : 0.f;
  const float scale = env * invd;

  float v[NR];
  float sp = 0.f, sc = s1;
  const float tc = 2.f * c1;
  #pragma unroll
  for (int r = 0; r < NR; ++r) {
    v[r] = sc * scale;
    const float sn = tc * sc - sp;
    sp = sc; sc = sn;
  }
  uint rec[16];
  #pragma unroll
  for (int r = 0; r < 10; ++r) rec[r] = f2bfu(v[2 * r]) | (f2bfu(v[2 * r + 1]) << 16);
  rec[10] = __float_as_uint(env);
  rec[11] = (uint)j;
  rec[12] = __float_as_uint(w0 * invd);
  rec[13] = __float_as_uint(w1 * invd);
  rec[14] = __float_as_uint(w2 * invd);
  rec[15] = 0u;

  uint4* dst = basisS + (size_t)pos * 4;
  dst[0] = make_uint4(rec[0], rec[1], rec[2], rec[3]);
  dst[1] = make_uint4(rec[4], rec[5], rec[6], rec[7]);
  dst[2] = make_uint4(rec[8], rec[9], rec[10], rec[11]);
  dst[3] = make_uint4(rec[12], rec[13], rec[14], rec[15]);
}

// ---------------------------------------------------------------------------
// Phase 1: x = silu(q @ W1 + b1) @ W2 + b2  -> bf16 x[N,384]
// ---------------------------------------------------------------------------
__global__ __launch_bounds__(128) void mlp_kernel(
    const float* __restrict__ q, const float* __restrict__ W1, const float* __restrict__ b1,
    const float* __restrict__ W2, const float* __restrict__ b2v, bf16* __restrict__ x)
{
  __shared__ float qL[APB][FD];
  __shared__ float hL[APB][FD];
  const int t = threadIdx.x;
  const int a0 = blockIdx.x * APB;

  #pragma unroll
  for (int a = 0; a < APB; ++a) qL[a][t] = q[(size_t)(a0 + a) * FD + t];
  __syncthreads();

  float hacc[APB];
  const float bb1 = b1[t];
  #pragma unroll
  for (int a = 0; a < APB; ++a) hacc[a] = bb1;

  for (int i = 0; i < FD; ++i) {
    const float w = W1[(size_t)i * FD + t];
    #pragma unroll
    for (int a = 0; a < APB; ++a) hacc[a] += qL[a][i] * w;
  }
  #pragma unroll
  for (int a = 0; a < APB; ++a) hL[a][t] = hacc[a] / (1.f + __expf(-hacc[a]));
  __syncthreads();

  float x0[APB], x1[APB], x2[APB];
  const float c0 = b2v[t], c1 = b2v[FD + t], c2 = b2v[2 * FD + t];
  #pragma unroll
  for (int a = 0; a < APB; ++a) { x0[a] = c0; x1[a] = c1; x2[a] = c2; }

  for (int i = 0; i < FD; ++i) {
    const float w0 = W2[(size_t)i * F3 + t];
    const float w1 = W2[(size_t)i * F3 + FD + t];
    const float w2 = W2[(size_t)i * F3 + 2 * FD + t];
    #pragma unroll
    for (int a = 0; a < APB; ++a) {
      const float hv = hL[a][i];
      x0[a] += hv * w0; x1[a] += hv * w1; x2[a] += hv * w2;
    }
  }
  #pragma unroll
  for (int a = 0; a < APB; ++a) {
    const int n = a0 + a;
    x[(size_t)n * F3 + t]          = __float2bfloat16(x0[a]);
    x[(size_t)n * F3 + FD + t]     = __float2bfloat16(x1[a]);
    x[(size_t)n * F3 + 2 * FD + t] = __float2bfloat16(x2[a]);
  }
}

// ---------------------------------------------------------------------------
// Phase 2: one block (384 thr = 6 waves) per destination atom.
// Records LDS-staged contiguously (64/chunk); per-edge metadata reads are
// LDS broadcasts. Filter dot = 10x v_dot2_f32_bf16. x/mu gathers are
// 4-deep software-pipelined (slot d issues edge k+4's load after consuming k).
// ---------------------------------------------------------------------------
__global__ __launch_bounds__(384) void gather_kernel(
    const float* __restrict__ q, const float* __restrict__ mu, const bf16* __restrict__ x,
    const float* __restrict__ Wf, const float* __restrict__ bfv,
    const int* __restrict__ off, const uint4* __restrict__ basisS,
    float* __restrict__ out)
{
  __shared__ uint4 stage4[256];          // 64 records x 64 B
  __shared__ float tmp[3][FD];
  const uint* sdata = (const uint*)stage4;
  const int t = threadIdx.x;
  const int i = blockIdx.x;
  const int ch = t >> 7;                 // 0,1,2 — wave-uniform
  const int c = t & (FD - 1);

  // Per-thread Wf column as 10 bf16 pairs (feeds v_dot2 directly).
  uint wfp[10];
  #pragma unroll
  for (int r = 0; r < 10; ++r)
    wfp[r] = f2bfu(Wf[(size_t)(2 * r) * F3 + t]) |
             (f2bfu(Wf[(size_t)(2 * r + 1) * F3 + t]) << 16);
  const float bias = bfv[t];

  const unsigned short* xs = (const unsigned short*)x;
  float a0 = 0.f, a1 = 0.f, a2 = 0.f;
  const int beg = off[i], end = off[i + 1];

  for (int cb = beg; cb < end; cb += 64) {
    const int nn = min(64, end - cb);
    __syncthreads();
    if (t < nn * 4) stage4[t] = basisS[(size_t)cb * 4 + t];   // stride-1 staging
    __syncthreads();

    unsigned short xp[4];
    float mp0[4], mp1[4], mp2[4];
    #pragma unroll
    for (int d = 0; d < 4; ++d) {
      if (d < nn) {
        const int jj = (int)sdata[d * 16 + 11];
        xp[d] = xs[(size_t)jj * F3 + t];
        if (ch == 2) {
          const float* mj = mu + (size_t)jj * F3 + c;
          mp0[d] = mj[0]; mp1[d] = mj[FD]; mp2[d] = mj[2 * FD];
        }
      }
    }

    for (int m = 0; m < 16; ++m) {
      const int k0 = m * 4;
      if (k0 >= nn) break;                        // block-uniform
      #pragma unroll
      for (int d = 0; d < 4; ++d) {
        const int k = k0 + d;
        if (k < nn) {
          const uint* rec = sdata + k * 16;       // LDS broadcast reads
          const float env = __uint_as_float(rec[10]);
          float f = env * bias;
          #pragma unroll
          for (int r = 0; r < 10; ++r) f = dot2acc(rec[r], wfp[r], f);

          const float xv = __uint_as_float((uint)xp[d] << 16);
          if (ch == 0) {
            a0 += f * xv;
          } else if (ch == 1) {
            const float dmuR = f * xv;
            a0 += dmuR * __uint_as_float(rec[12]);
            a1 += dmuR * __uint_as_float(rec[13]);
            a2 += dmuR * __uint_as_float(rec[14]);
          } else {
            const float dm = f * xv;
            a0 += dm * mp0[d]; a1 += dm * mp1[d]; a2 += dm * mp2[d];
          }
          // refill slot d with edge k+4 (pipeline depth 4)
          const int kd = k + 4;
          if (kd < nn) {
            const int jj = (int)sdata[kd * 16 + 11];
            xp[d] = xs[(size_t)jj * F3 + t];
            if (ch == 2) {
              const float* mj = mu + (size_t)jj * F3 + c;
              mp0[d] = mj[0]; mp1[d] = mj[FD]; mp2[d] = mj[2 * FD];
            }
          }
        }
      }
    }
  }

  if (ch == 1) { tmp[0][c] = a0; tmp[1][c] = a1; tmp[2][c] = a2; }
  __syncthreads();
  if (ch == 0) {
    out[(size_t)i * FD + c] = q[(size_t)i * FD + c] + a0;
  } else if (ch == 2) {
    const size_t NQ = (size_t)NATOMS * FD;
    const size_t mi = (size_t)i * F3;
    out[NQ + mi + c]          = mu[mi + c]          + tmp[0][c] + a0;
    out[NQ + mi + FD + c]     = mu[mi + FD + c]     + tmp[1][c] + a1;
    out[NQ + mi + 2 * FD + c] = mu[mi + 2 * FD + c] + tmp[2][c] + a2;
  }
}

extern "C" void kernel_launch(void* const* d_in, const int* in_sizes, int n_in,
                              void* d_out, int out_size, void* d_ws, size_t ws_size,
                              hipStream_t stream) {
  const float* q   = (const float*)d_in[0];
  const float* mu  = (const float*)d_in[1];
  const int*   eix = (const int*)d_in[2];
  const float* ew  = (const float*)d_in[3];
  const float* W1  = (const float*)d_in[4];
  const float* b1  = (const float*)d_in[5];
  const float* W2  = (const float*)d_in[6];
  const float* b2v = (const float*)d_in[7];
  const float* Wf  = (const float*)d_in[8];
  const float* bfv = (const float*)d_in[9];
  float* out = (float*)d_out;

  // Workspace (~56.5 MB): [basisS 64B*E | x bf16 N*384 | off N+1 | cnt N | cursor N]
  char* w = (char*)d_ws;
  uint4* basisS = (uint4*)w;  w += (size_t)NEDGES * 64;
  bf16*  x      = (bf16*)w;   w += (size_t)NATOMS * F3 * sizeof(bf16);
  int*   off    = (int*)w;    w += (size_t)(NATOMS + 1) * sizeof(int);
  int*   cnt    = (int*)w;    w += (size_t)NATOMS * sizeof(int);
  int*   cursor = (int*)w;

  hipMemsetAsync(cnt, 0, (size_t)NATOMS * sizeof(int), stream);

  hist_kernel<<<(NEDGES + 255) / 256, 256, 0, stream>>>(eix, cnt);
  scan_kernel<<<1, 512, 0, stream>>>(cnt, off);
  hipMemcpyAsync(cursor, off, (size_t)NATOMS * sizeof(int),
                 hipMemcpyDeviceToDevice, stream);
  prep_kernel<<<(NEDGES + 255) / 256, 256, 0, stream>>>(eix, ew, cursor, basisS);

  mlp_kernel<<<NATOMS / APB, 128, 0, stream>>>(q, W1, b1, W2, b2v, x);

  gather_kernel<<<NATOMS, 384, 0, stream>>>(q, mu, x, Wf, bfv, off, basisS, out);
}